// Round 5
// baseline (340.445 us; speedup 1.0000x reference)
//
#include <hip/hip_runtime.h>
#include <hip/hip_bf16.h>
#include <stdint.h>

// LatticeMultiHeadAttention on MI355X (gfx950). f32 in/out, bf16 MFMA inside.
// Kuramoto phase inputs are softmax-shift-invariant -> unused.
//
// R5: (1) prep weight-pack rewritten as gather-read transpose (old version did
// 2B scatter stores, 64 lines/wave-inst -> ~50us). (2) X f32->bf16 conversion
// folded into gemm_qkv staging: sB staged as f32 via global_load_lds with
// source-permute XOR swizzle, cvt to bf16 at fragment build. Kills the 144 MB
// X round-trip. attn/gemm_out unchanged (R4 XCD swizzle kept).

typedef unsigned short u16;
typedef __bf16 bf16_t;
typedef bf16_t bf16x8 __attribute__((ext_vector_type(8)));
typedef float f32x4 __attribute__((ext_vector_type(4)));

#define DEVI static __device__ __forceinline__
#define MFMA16(a, b, c) __builtin_amdgcn_mfma_f32_16x16x32_bf16((a), (b), (c), 0, 0, 0)

DEVI void gload_lds16(const void* g, void* l) {
  __builtin_amdgcn_global_load_lds((__attribute__((address_space(1))) void*)g,
                                   (__attribute__((address_space(3))) void*)l, 16, 0, 0);
}

DEVI u16 f2bf(float x) {
  bf16_t b = (bf16_t)x;
  u16 u;
  __builtin_memcpy(&u, &b, 2);
  return u;
}

// ---------------------------------------------------------------------------
// Weight pack via gather-read transpose. 1024 blocks x 256 threads.
// mat<3: WT[h*64+j][k] = W[h][k][j]  (16 tiles/head x 16 heads = 256 blocks)
// mat=3: WoT[c][d]     = Wo[d][c]    (256 64x64 tiles)
// Reads: strided f32 gathers with 16-32x L1 reuse; writes: 2x16B coalesced.
__global__ __launch_bounds__(256) void prep_w(const float* __restrict__ Wq,
                                              const float* __restrict__ Wk,
                                              const float* __restrict__ Wv,
                                              const float* __restrict__ Wo,
                                              u16* __restrict__ ws) {
  int blk = blockIdx.x;  // 0..1023
  int mat = blk >> 8, t = blk & 255;
  const float* src = (mat == 0) ? Wq : (mat == 1) ? Wk : (mat == 2) ? Wv : Wo;
  u16* dst = ws + (size_t)mat * 1048576;
  int j = threadIdx.x >> 2;  // 0..63
  int c = threadIdx.x & 3;   // 0..3 (16-wide k chunk)
  const float* sp;
  int stride, row, col0;
  if (mat < 3) {
    int h = t >> 4, kt = t & 15;
    int k0 = kt * 64 + c * 16;
    sp = src + h * 65536 + (size_t)k0 * 64 + j;
    stride = 64;
    row = h * 64 + j;
    col0 = k0;
  } else {
    int ct = t >> 4, dt = t & 15;
    int d0 = dt * 64 + c * 16;
    sp = src + (size_t)d0 * 1024 + ct * 64 + j;
    stride = 1024;
    row = ct * 64 + j;
    col0 = d0;
  }
  u16 v[16];
#pragma unroll
  for (int i = 0; i < 16; i++) v[i] = f2bf(sp[(size_t)i * stride]);
  uint4 a, b2;
  __builtin_memcpy(&a, v, 16);
  __builtin_memcpy(&b2, v + 8, 16);
  *(uint4*)(dst + (size_t)row * 1024 + col0) = a;
  *(uint4*)(dst + (size_t)row * 1024 + col0 + 8) = b2;
}

// ---------------------------------------------------------------------------
// QKV projections, one dispatch. D[m][n]=sum_k A[m][k]*B[n][k], A bf16 WT,
// B = f32 activations staged directly (swizzled), cvt at fragment build.
// XCD swizzle: xcd=id%8 owns n-groups [xcd*24, xcd*24+24).
__global__ __launch_bounds__(256) void gemm_qkv(const u16* __restrict__ WT,
                                                const float* __restrict__ Xq,
                                                const float* __restrict__ Xk,
                                                const float* __restrict__ Xv,
                                                u16* __restrict__ Qw,
                                                u16* __restrict__ Kw,
                                                u16* __restrict__ Vw) {
  __shared__ __align__(16) u16 sA[128 * 32];    // 8 KB bf16
  __shared__ __align__(16) float sB[128 * 32];  // 16 KB f32 (swizzled rows)
  int id = blockIdx.x + 8 * (blockIdx.y + 64 * blockIdx.z);  // 0..1535
  int xcd = id & 7, jj = id >> 3;
  int mtile = jj & 7;
  int g = xcd * 24 + (jj >> 3);
  int z = g >> 6;   // 0..2
  int nt = g & 63;  // 0..63
  const u16* A = WT + (size_t)z * 1048576;
  const float* Bx = (z == 0) ? Xq : (z == 1) ? Xk : Xv;
  u16* out = (z == 0) ? Qw : (z == 1) ? Kw : Vw;
  float oscale = (z == 0) ? 0.125f : 1.0f;

  int tid = threadIdx.x;
  int wid = tid >> 6, lane = tid & 63, quad = lane >> 4, l16 = lane & 15;
  int wm = wid >> 1, wn = wid & 1;
  int m0 = mtile * 128, n0 = nt * 128;

  f32x4 acc[4][4];
#pragma unroll
  for (int i = 0; i < 4; i++)
#pragma unroll
    for (int j2 = 0; j2 < 4; j2++) acc[i][j2] = {0.f, 0.f, 0.f, 0.f};

  for (int k0 = 0; k0 < 1024; k0 += 32) {
    // A (bf16): 2 insts, rows of 64 B
#pragma unroll
    for (int p = 0; p < 2; p++) {
      int cl = p * 256 + tid;
      int r = cl >> 2, kc = cl & 3;
      gload_lds16(A + (size_t)(m0 + r) * 1024 + k0 + kc * 8,
                  (char*)sA + (p * 256 + wid * 64) * 16);
    }
    // B (f32): 4 insts, rows of 128 B, source-permute swizzle chunk^(row&7)
#pragma unroll
    for (int p = 0; p < 4; p++) {
      int cl = p * 256 + tid;
      int r = cl >> 3, c = cl & 7, gg = c ^ (r & 7);
      gload_lds16(Bx + (size_t)(n0 + r) * 1024 + k0 + gg * 4,
                  (char*)sB + (p * 256 + wid * 64) * 16);
    }
    __syncthreads();
    bf16x8 af[4], bfr[4];
#pragma unroll
    for (int mt = 0; mt < 4; mt++)
      af[mt] = *(const bf16x8*)((const char*)sA + ((wm * 64 + mt * 16 + l16) * 64 + quad * 16));
#pragma unroll
    for (int ntf = 0; ntf < 4; ntf++) {
      int row = wn * 64 + ntf * 16 + l16;
      const char* rp = (const char*)sB + row * 128;
      int c0 = (quad * 2) ^ (row & 7);
      int c1 = (quad * 2 + 1) ^ (row & 7);
      f32x4 x0 = *(const f32x4*)(rp + c0 * 16);
      f32x4 x1 = *(const f32x4*)(rp + c1 * 16);
      bf16x8 f;
      f[0] = (bf16_t)x0[0]; f[1] = (bf16_t)x0[1];
      f[2] = (bf16_t)x0[2]; f[3] = (bf16_t)x0[3];
      f[4] = (bf16_t)x1[0]; f[5] = (bf16_t)x1[1];
      f[6] = (bf16_t)x1[2]; f[7] = (bf16_t)x1[3];
      bfr[ntf] = f;
    }
#pragma unroll
    for (int mt = 0; mt < 4; mt++)
#pragma unroll
      for (int ntf = 0; ntf < 4; ntf++) acc[mt][ntf] = MFMA16(af[mt], bfr[ntf], acc[mt][ntf]);
    __syncthreads();
  }

#pragma unroll
  for (int mt = 0; mt < 4; mt++) {
    int m = m0 + wm * 64 + mt * 16 + quad * 4;
#pragma unroll
    for (int ntf = 0; ntf < 4; ntf++) {
      int n = n0 + wn * 64 + ntf * 16 + l16;
      f32x4 v = acc[mt][ntf];
      int b = n >> 10, l = n & 1023, h = m >> 6, dk = m & 63;
      if (z < 2) {
        ushort4 st;
        st.x = f2bf(v[0] * oscale); st.y = f2bf(v[1] * oscale);
        st.z = f2bf(v[2] * oscale); st.w = f2bf(v[3] * oscale);
        *(ushort4*)(out + ((size_t)((b * 16 + h) * 1024 + l) * 64 + dk)) = st;
      } else {
        size_t base = ((size_t)((b * 16 + h) * 64 + dk)) * 1024 + l;
        out[base] = f2bf(v[0]);
        out[base + 1024] = f2bf(v[1]);
        out[base + 2048] = f2bf(v[2]);
        out[base + 3072] = f2bf(v[3]);
      }
    }
  }
}

// ---------------------------------------------------------------------------
// Out-projection: f32 out[row][d] = sum_k WoT[d][k]*Cw[row][k] + bias[d]
// XCD swizzle: xcd owns n-tiles [xcd*8, xcd*8+8).
__global__ __launch_bounds__(256) void gemm_out(const u16* __restrict__ A,
                                                const u16* __restrict__ Bx,
                                                float* __restrict__ outf,
                                                const float* __restrict__ bias) {
  __shared__ __align__(16) u16 sA[128 * 32];
  __shared__ __align__(16) u16 sB[128 * 32];
  int id = blockIdx.x + 8 * blockIdx.y;  // 0..511
  int xcd = id & 7, j = id >> 3;
  int mtile = j & 7;
  int nt = xcd * 8 + (j >> 3);
  int tid = threadIdx.x;
  int wid = tid >> 6, lane = tid & 63, quad = lane >> 4, l16 = lane & 15;
  int wm = wid >> 1, wn = wid & 1;
  int m0 = mtile * 128, n0 = nt * 128;

  f32x4 acc[4][4];
#pragma unroll
  for (int i = 0; i < 4; i++)
#pragma unroll
    for (int jj = 0; jj < 4; jj++) acc[i][jj] = {0.f, 0.f, 0.f, 0.f};

  for (int k0 = 0; k0 < 1024; k0 += 32) {
#pragma unroll
    for (int p = 0; p < 2; p++) {
      int cl = p * 256 + tid;
      int r = cl >> 2, kc = cl & 3;
      gload_lds16(A + (size_t)(m0 + r) * 1024 + k0 + kc * 8,
                  (char*)sA + (p * 256 + wid * 64) * 16);
      gload_lds16(Bx + (size_t)(n0 + r) * 1024 + k0 + kc * 8,
                  (char*)sB + (p * 256 + wid * 64) * 16);
    }
    __syncthreads();
    bf16x8 af[4], bfr[4];
#pragma unroll
    for (int mt = 0; mt < 4; mt++)
      af[mt] = *(const bf16x8*)((const char*)sA + ((wm * 64 + mt * 16 + l16) * 64 + quad * 16));
#pragma unroll
    for (int ntf = 0; ntf < 4; ntf++)
      bfr[ntf] = *(const bf16x8*)((const char*)sB + ((wn * 64 + ntf * 16 + l16) * 64 + quad * 16));
#pragma unroll
    for (int mt = 0; mt < 4; mt++)
#pragma unroll
      for (int ntf = 0; ntf < 4; ntf++) acc[mt][ntf] = MFMA16(af[mt], bfr[ntf], acc[mt][ntf]);
    __syncthreads();
  }

#pragma unroll
  for (int mt = 0; mt < 4; mt++) {
    int m = m0 + wm * 64 + mt * 16 + quad * 4;
#pragma unroll
    for (int ntf = 0; ntf < 4; ntf++) {
      int n = n0 + wn * 64 + ntf * 16 + l16;
      f32x4 v = acc[mt][ntf];
      float4 st;
      st.x = v[0] + bias[m];
      st.y = v[1] + bias[m + 1];
      st.z = v[2] + bias[m + 2];
      st.w = v[3] + bias[m + 3];
      *(float4*)(outf + ((size_t)n * 1024 + m)) = st;
    }
  }
}

// ---------------------------------------------------------------------------
// Attention: block = 4 waves, 128 q (wave owns 32 q = 2 B-frags).
// S^T = K Q^T (Q pre-scaled); exp (no max-sub); P in dead sQ region;
// O^T = V^T P^T. XCD swizzle: 8 q-blocks of one (b,h) share K/V -> same XCD.
__global__ __launch_bounds__(256, 4) void attn_k(const u16* __restrict__ Q,
                                                 const u16* __restrict__ K,
                                                 const u16* __restrict__ VT,
                                                 u16* __restrict__ CTX) {
  __shared__ __align__(16) u16 sQ[128 * 64];  // 16 KB; reused as sP after bq load
  __shared__ __align__(16) u16 sK[64 * 64];   // 8 KB
  __shared__ __align__(16) u16 sV[64 * 64];   // 8 KB
  int tid = threadIdx.x;
  int wid = tid >> 6, lane = tid & 63, quad = lane >> 4, l16 = lane & 15;
  int id = blockIdx.x + 8 * blockIdx.y;  // 0..1023
  int xcd = id & 7, j = id >> 3;
  int qt = j & 7;
  int bh = xcd * 16 + (j >> 3);
  const u16* Qb = Q + (size_t)bh * 65536;
  const u16* Kb = K + (size_t)bh * 65536;
  const u16* Vb = VT + (size_t)bh * 65536;
  int q0 = qt * 128;

#pragma unroll
  for (int p = 0; p < 4; p++) {
    int cl = p * 256 + tid;
    int r = cl >> 3, c = cl & 7, g = c ^ (r & 7);
    gload_lds16(Qb + (size_t)(q0 + r) * 64 + g * 8, (char*)sQ + (p * 256 + wid * 64) * 16);
  }
  __syncthreads();

  bf16x8 bq[2][2];
#pragma unroll
  for (int qf = 0; qf < 2; qf++) {
    int row = wid * 32 + qf * 16 + l16;
#pragma unroll
    for (int ks = 0; ks < 2; ks++) {
      int ch = (ks * 4 + quad) ^ (row & 7);
      bq[qf][ks] = *(const bf16x8*)((const char*)sQ + row * 128 + ch * 16);
    }
  }
  // first K-loop barrier drains these reads before any sP write lands.

  u16* sPw = sQ + wid * 2048;  // per-wave 32 rows x 64 lk (4 KB)

  f32x4 oacc[4][2];
#pragma unroll
  for (int i = 0; i < 4; i++) {
    oacc[i][0] = {0.f, 0.f, 0.f, 0.f};
    oacc[i][1] = {0.f, 0.f, 0.f, 0.f};
  }
  float lsum[2] = {0.f, 0.f};

  for (int lk0 = 0; lk0 < 1024; lk0 += 64) {
#pragma unroll
    for (int p = 0; p < 2; p++) {
      int cl = p * 256 + tid;
      int r = cl >> 3, c = cl & 7, g = c ^ (r & 7);
      gload_lds16(Kb + (size_t)(lk0 + r) * 64 + g * 8, (char*)sK + (p * 256 + wid * 64) * 16);
      gload_lds16(Vb + (size_t)r * 1024 + lk0 + g * 8, (char*)sV + (p * 256 + wid * 64) * 16);
    }
    __syncthreads();

    f32x4 s[4][2];
#pragma unroll
    for (int mt = 0; mt < 4; mt++) {
      s[mt][0] = {0.f, 0.f, 0.f, 0.f};
      s[mt][1] = {0.f, 0.f, 0.f, 0.f};
    }
#pragma unroll
    for (int ks = 0; ks < 2; ks++) {
#pragma unroll
      for (int mt = 0; mt < 4; mt++) {
        int row = mt * 16 + l16;
        int ch = (ks * 4 + quad) ^ (row & 7);
        bf16x8 a = *(const bf16x8*)((const char*)sK + row * 128 + ch * 16);
        s[mt][0] = MFMA16(a, bq[0][ks], s[mt][0]);
        s[mt][1] = MFMA16(a, bq[1][ks], s[mt][1]);
      }
    }

#pragma unroll
    for (int qf = 0; qf < 2; qf++) {
      int row = qf * 16 + l16;
#pragma unroll
      for (int mt = 0; mt < 4; mt++) {
        float p0 = __expf(s[mt][qf][0]);
        float p1 = __expf(s[mt][qf][1]);
        float p2 = __expf(s[mt][qf][2]);
        float p3 = __expf(s[mt][qf][3]);
        lsum[qf] += (p0 + p1) + (p2 + p3);
        ushort4 st;
        st.x = f2bf(p0); st.y = f2bf(p1); st.z = f2bf(p2); st.w = f2bf(p3);
        int ch = (2 * mt + (quad >> 1)) ^ (row & 7);
        *(ushort4*)((char*)sPw + row * 128 + ch * 16 + (quad & 1) * 8) = st;
      }
    }
    asm volatile("s_waitcnt lgkmcnt(0)" ::: "memory");  // same-wave P write->read

    bf16x8 bp[2][2];
#pragma unroll
    for (int qf = 0; qf < 2; qf++) {
      int row = qf * 16 + l16;
#pragma unroll
      for (int c = 0; c < 2; c++) {
        int ch = (c * 4 + quad) ^ (row & 7);
        bp[qf][c] = *(const bf16x8*)((const char*)sPw + row * 128 + ch * 16);
      }
    }
#pragma unroll
    for (int c = 0; c < 2; c++) {
#pragma unroll
      for (int mt = 0; mt < 4; mt++) {
        int row = mt * 16 + l16;
        int ch = (c * 4 + quad) ^ (row & 7);
        bf16x8 a = *(const bf16x8*)((const char*)sV + row * 128 + ch * 16);
        oacc[mt][0] = MFMA16(a, bp[0][c], oacc[mt][0]);
        oacc[mt][1] = MFMA16(a, bp[1][c], oacc[mt][1]);
      }
    }
    __syncthreads();
  }

#pragma unroll
  for (int qf = 0; qf < 2; qf++) {
    lsum[qf] += __shfl_xor(lsum[qf], 16, 64);
    lsum[qf] += __shfl_xor(lsum[qf], 32, 64);
  }
  float inv0 = 1.f / lsum[0], inv1 = 1.f / lsum[1];

  int b = bh >> 4, h = bh & 15;
#pragma unroll
  for (int qf = 0; qf < 2; qf++) {
    int qg = q0 + wid * 32 + qf * 16 + l16;
    float inv = qf ? inv1 : inv0;
#pragma unroll
    for (int mt = 0; mt < 4; mt++) {
      int dk = mt * 16 + quad * 4;
      ushort4 st;
      st.x = f2bf(oacc[mt][qf][0] * inv);
      st.y = f2bf(oacc[mt][qf][1] * inv);
      st.z = f2bf(oacc[mt][qf][2] * inv);
      st.w = f2bf(oacc[mt][qf][3] * inv);
      *(ushort4*)(CTX + (((size_t)(b * 1024 + qg) * 16 + h) * 64 + dk)) = st;
    }
  }
}

// ---------------------------------------------------------------------------
extern "C" void kernel_launch(void* const* d_in, const int* in_sizes, int n_in,
                              void* d_out, int out_size, void* d_ws, size_t ws_size,
                              hipStream_t stream) {
  (void)in_sizes; (void)n_in; (void)out_size; (void)ws_size;
  const float* query = (const float*)d_in[0];
  const float* key_ = (const float*)d_in[1];
  const float* value = (const float*)d_in[2];
  const float* Wq = (const float*)d_in[3];
  const float* Wk = (const float*)d_in[4];
  const float* Wv = (const float*)d_in[5];
  const float* Wo = (const float*)d_in[6];
  const float* bo = (const float*)d_in[7];

  u16* ws = (u16*)d_ws;
  u16* WT = ws;               // 4 x [1024][1024] bf16 (WTq,WTk,WTv,WoT) = 8 MB
  u16* Qw = ws + 4194304;     // [B,H,L,DK] bf16
  u16* Kw = ws + 12582912;    // [B,H,L,DK]
  u16* Vw = ws + 20971520;    // [B,H,DK,L]
  u16* Cw = ws + 29360128;    // [B,L,H,DK] == [8192][1024]
  float* outp = (float*)d_out;

  prep_w<<<1024, 256, 0, stream>>>(Wq, Wk, Wv, Wo, ws);
  gemm_qkv<<<dim3(8, 64, 3), 256, 0, stream>>>(WT, query, key_, value, Qw, Kw, Vw);
  attn_k<<<dim3(8, 128), 256, 0, stream>>>(Qw, Kw, Vw, Cw);
  gemm_out<<<dim3(8, 64), 256, 0, stream>>>(WT + 3145728, Cw, outp, bo);
}

// Round 6
// 308.215 us; speedup vs baseline: 1.1046x; 1.1046x over previous
//
#include <hip/hip_runtime.h>
#include <hip/hip_bf16.h>
#include <stdint.h>

// LatticeMultiHeadAttention on MI355X (gfx950). f32 in/out, bf16 MFMA inside.
// Kuramoto phase inputs are softmax-shift-invariant -> unused.
//
// R6: revert R5's cvt-in-GEMM (broke LDS->MFMA pipelining: MfmaUtil 29->14,
// qkv 72->145us). Keep: R5's gather-read weight transpose (scatter prep was
// ~50us), R4's XCD swizzles + bf16-staged gemm_qkv. prep = weights + X cvt in
// one dispatch.

typedef unsigned short u16;
typedef __bf16 bf16_t;
typedef bf16_t bf16x8 __attribute__((ext_vector_type(8)));
typedef float f32x4 __attribute__((ext_vector_type(4)));

#define DEVI static __device__ __forceinline__
#define MFMA16(a, b, c) __builtin_amdgcn_mfma_f32_16x16x32_bf16((a), (b), (c), 0, 0, 0)

DEVI void gload_lds16(const void* g, void* l) {
  __builtin_amdgcn_global_load_lds((__attribute__((address_space(1))) void*)g,
                                   (__attribute__((address_space(3))) void*)l, 16, 0, 0);
}

DEVI u16 f2bf(float x) {
  bf16_t b = (bf16_t)x;
  u16 u;
  __builtin_memcpy(&u, &b, 2);
  return u;
}

// ---------------------------------------------------------------------------
// prep: blocks 0..1023   -> weight transpose via gather reads (L1-reused
//                           strided f32 loads, coalesced 16B writes)
//       blocks 1024..25599 -> X f32 -> bf16 copies (4 elems/thread)
__global__ __launch_bounds__(256) void prep(const float* __restrict__ Wq,
                                            const float* __restrict__ Wk,
                                            const float* __restrict__ Wv,
                                            const float* __restrict__ Wo,
                                            const float* __restrict__ q,
                                            const float* __restrict__ k,
                                            const float* __restrict__ v,
                                            u16* __restrict__ ws) {
  int bx = blockIdx.x;
  if (bx < 1024) {
    int mat = bx >> 8, t = bx & 255;
    const float* src = (mat == 0) ? Wq : (mat == 1) ? Wk : (mat == 2) ? Wv : Wo;
    u16* dst = ws + (size_t)mat * 1048576;
    int j = threadIdx.x >> 2;  // 0..63
    int c = threadIdx.x & 3;   // 0..3 (16-wide chunk)
    const float* sp;
    int stride, row, col0;
    if (mat < 3) {
      int h = t >> 4, kt = t & 15;
      int k0 = kt * 64 + c * 16;
      sp = src + h * 65536 + (size_t)k0 * 64 + j;
      stride = 64;
      row = h * 64 + j;
      col0 = k0;
    } else {
      int ct = t >> 4, dt = t & 15;
      int d0 = dt * 64 + c * 16;
      sp = src + (size_t)d0 * 1024 + ct * 64 + j;
      stride = 1024;
      row = ct * 64 + j;
      col0 = d0;
    }
    u16 vv[16];
#pragma unroll
    for (int i = 0; i < 16; i++) vv[i] = f2bf(sp[(size_t)i * stride]);
    uint4 a, b2;
    __builtin_memcpy(&a, vv, 16);
    __builtin_memcpy(&b2, vv + 8, 16);
    *(uint4*)(dst + (size_t)row * 1024 + col0) = a;
    *(uint4*)(dst + (size_t)row * 1024 + col0 + 8) = b2;
  } else {
    int id = (bx - 1024) * 256 + threadIdx.x;  // 0..6291455, 4 elems each
    int t = id >> 21;
    size_t rem = (size_t)(id & 2097151) * 4;
    const float* src = (t == 0) ? q : (t == 1) ? k : v;
    float4 a = *(const float4*)(src + rem);
    ushort4 st;
    st.x = f2bf(a.x); st.y = f2bf(a.y); st.z = f2bf(a.z); st.w = f2bf(a.w);
    *(ushort4*)(ws + 4194304 + (size_t)t * 8388608 + rem) = st;
  }
}

// ---------------------------------------------------------------------------
// QKV projections, one dispatch. D[m][n]=sum_k A[m][k]B[n][k], all bf16 LDS.
// XCD swizzle: xcd=id%8 owns n-groups [xcd*24, xcd*24+24); the 8 m-tiles of
// one n-group are consecutive on that XCD (X tile + W stay in its L2).
__global__ __launch_bounds__(256) void gemm_qkv(const u16* __restrict__ WT,
                                                const u16* __restrict__ X,
                                                u16* __restrict__ Qw,
                                                u16* __restrict__ Kw,
                                                u16* __restrict__ Vw) {
  __shared__ __align__(16) u16 sA[128 * 32];
  __shared__ __align__(16) u16 sB[128 * 32];
  int id = blockIdx.x + 8 * (blockIdx.y + 64 * blockIdx.z);  // 0..1535
  int xcd = id & 7, jj = id >> 3;
  int mtile = jj & 7;
  int g = xcd * 24 + (jj >> 3);
  int z = g >> 6;   // 0..2
  int nt = g & 63;  // 0..63
  const u16* A = WT + (size_t)z * 1048576;
  const u16* Bx = X + (size_t)z * 8388608;
  u16* out = (z == 0) ? Qw : (z == 1) ? Kw : Vw;
  float oscale = (z == 0) ? 0.125f : 1.0f;

  int tid = threadIdx.x;
  int wid = tid >> 6, lane = tid & 63, quad = lane >> 4, l16 = lane & 15;
  int wm = wid >> 1, wn = wid & 1;
  int m0 = mtile * 128, n0 = nt * 128;

  f32x4 acc[4][4];
#pragma unroll
  for (int i = 0; i < 4; i++)
#pragma unroll
    for (int j2 = 0; j2 < 4; j2++) acc[i][j2] = {0.f, 0.f, 0.f, 0.f};

  for (int k0 = 0; k0 < 1024; k0 += 32) {
#pragma unroll
    for (int p = 0; p < 2; p++) {
      int cl = p * 256 + tid;
      int r = cl >> 2, kc = cl & 3;
      gload_lds16(A + (size_t)(m0 + r) * 1024 + k0 + kc * 8,
                  (char*)sA + (p * 256 + wid * 64) * 16);
      gload_lds16(Bx + (size_t)(n0 + r) * 1024 + k0 + kc * 8,
                  (char*)sB + (p * 256 + wid * 64) * 16);
    }
    __syncthreads();
    bf16x8 af[4], bfr[4];
#pragma unroll
    for (int mt = 0; mt < 4; mt++)
      af[mt] = *(const bf16x8*)((const char*)sA + ((wm * 64 + mt * 16 + l16) * 64 + quad * 16));
#pragma unroll
    for (int ntf = 0; ntf < 4; ntf++)
      bfr[ntf] = *(const bf16x8*)((const char*)sB + ((wn * 64 + ntf * 16 + l16) * 64 + quad * 16));
#pragma unroll
    for (int mt = 0; mt < 4; mt++)
#pragma unroll
      for (int ntf = 0; ntf < 4; ntf++) acc[mt][ntf] = MFMA16(af[mt], bfr[ntf], acc[mt][ntf]);
    __syncthreads();
  }

#pragma unroll
  for (int mt = 0; mt < 4; mt++) {
    int m = m0 + wm * 64 + mt * 16 + quad * 4;
#pragma unroll
    for (int ntf = 0; ntf < 4; ntf++) {
      int n = n0 + wn * 64 + ntf * 16 + l16;
      f32x4 v = acc[mt][ntf];
      int b = n >> 10, l = n & 1023, h = m >> 6, dk = m & 63;
      if (z < 2) {
        ushort4 st;
        st.x = f2bf(v[0] * oscale); st.y = f2bf(v[1] * oscale);
        st.z = f2bf(v[2] * oscale); st.w = f2bf(v[3] * oscale);
        *(ushort4*)(out + ((size_t)((b * 16 + h) * 1024 + l) * 64 + dk)) = st;
      } else {
        size_t base = ((size_t)((b * 16 + h) * 64 + dk)) * 1024 + l;
        out[base] = f2bf(v[0]);
        out[base + 1024] = f2bf(v[1]);
        out[base + 2048] = f2bf(v[2]);
        out[base + 3072] = f2bf(v[3]);
      }
    }
  }
}

// ---------------------------------------------------------------------------
// Out-projection: f32 out[row][d] = sum_k WoT[d][k]*Cw[row][k] + bias[d]
// XCD swizzle: xcd owns n-tiles [xcd*8, xcd*8+8).
__global__ __launch_bounds__(256) void gemm_out(const u16* __restrict__ A,
                                                const u16* __restrict__ Bx,
                                                float* __restrict__ outf,
                                                const float* __restrict__ bias) {
  __shared__ __align__(16) u16 sA[128 * 32];
  __shared__ __align__(16) u16 sB[128 * 32];
  int id = blockIdx.x + 8 * blockIdx.y;  // 0..511
  int xcd = id & 7, j = id >> 3;
  int mtile = j & 7;
  int nt = xcd * 8 + (j >> 3);
  int tid = threadIdx.x;
  int wid = tid >> 6, lane = tid & 63, quad = lane >> 4, l16 = lane & 15;
  int wm = wid >> 1, wn = wid & 1;
  int m0 = mtile * 128, n0 = nt * 128;

  f32x4 acc[4][4];
#pragma unroll
  for (int i = 0; i < 4; i++)
#pragma unroll
    for (int jj = 0; jj < 4; jj++) acc[i][jj] = {0.f, 0.f, 0.f, 0.f};

  for (int k0 = 0; k0 < 1024; k0 += 32) {
#pragma unroll
    for (int p = 0; p < 2; p++) {
      int cl = p * 256 + tid;
      int r = cl >> 2, kc = cl & 3;
      gload_lds16(A + (size_t)(m0 + r) * 1024 + k0 + kc * 8,
                  (char*)sA + (p * 256 + wid * 64) * 16);
      gload_lds16(Bx + (size_t)(n0 + r) * 1024 + k0 + kc * 8,
                  (char*)sB + (p * 256 + wid * 64) * 16);
    }
    __syncthreads();
    bf16x8 af[4], bfr[4];
#pragma unroll
    for (int mt = 0; mt < 4; mt++)
      af[mt] = *(const bf16x8*)((const char*)sA + ((wm * 64 + mt * 16 + l16) * 64 + quad * 16));
#pragma unroll
    for (int ntf = 0; ntf < 4; ntf++)
      bfr[ntf] = *(const bf16x8*)((const char*)sB + ((wn * 64 + ntf * 16 + l16) * 64 + quad * 16));
#pragma unroll
    for (int mt = 0; mt < 4; mt++)
#pragma unroll
      for (int ntf = 0; ntf < 4; ntf++) acc[mt][ntf] = MFMA16(af[mt], bfr[ntf], acc[mt][ntf]);
    __syncthreads();
  }

#pragma unroll
  for (int mt = 0; mt < 4; mt++) {
    int m = m0 + wm * 64 + mt * 16 + quad * 4;
#pragma unroll
    for (int ntf = 0; ntf < 4; ntf++) {
      int n = n0 + wn * 64 + ntf * 16 + l16;
      f32x4 v = acc[mt][ntf];
      float4 st;
      st.x = v[0] + bias[m];
      st.y = v[1] + bias[m + 1];
      st.z = v[2] + bias[m + 2];
      st.w = v[3] + bias[m + 3];
      *(float4*)(outf + ((size_t)n * 1024 + m)) = st;
    }
  }
}

// ---------------------------------------------------------------------------
// Attention: block = 4 waves, 128 q (wave owns 32 q = 2 B-frags).
// S^T = K Q^T (Q pre-scaled); exp (no max-sub); P in dead sQ region;
// O^T = V^T P^T. XCD swizzle: 8 q-blocks of one (b,h) share K/V -> same XCD.
__global__ __launch_bounds__(256, 4) void attn_k(const u16* __restrict__ Q,
                                                 const u16* __restrict__ K,
                                                 const u16* __restrict__ VT,
                                                 u16* __restrict__ CTX) {
  __shared__ __align__(16) u16 sQ[128 * 64];  // 16 KB; reused as sP after bq load
  __shared__ __align__(16) u16 sK[64 * 64];   // 8 KB
  __shared__ __align__(16) u16 sV[64 * 64];   // 8 KB
  int tid = threadIdx.x;
  int wid = tid >> 6, lane = tid & 63, quad = lane >> 4, l16 = lane & 15;
  int id = blockIdx.x + 8 * blockIdx.y;  // 0..1023
  int xcd = id & 7, j = id >> 3;
  int qt = j & 7;
  int bh = xcd * 16 + (j >> 3);
  const u16* Qb = Q + (size_t)bh * 65536;
  const u16* Kb = K + (size_t)bh * 65536;
  const u16* Vb = VT + (size_t)bh * 65536;
  int q0 = qt * 128;

#pragma unroll
  for (int p = 0; p < 4; p++) {
    int cl = p * 256 + tid;
    int r = cl >> 3, c = cl & 7, g = c ^ (r & 7);
    gload_lds16(Qb + (size_t)(q0 + r) * 64 + g * 8, (char*)sQ + (p * 256 + wid * 64) * 16);
  }
  __syncthreads();

  bf16x8 bq[2][2];
#pragma unroll
  for (int qf = 0; qf < 2; qf++) {
    int row = wid * 32 + qf * 16 + l16;
#pragma unroll
    for (int ks = 0; ks < 2; ks++) {
      int ch = (ks * 4 + quad) ^ (row & 7);
      bq[qf][ks] = *(const bf16x8*)((const char*)sQ + row * 128 + ch * 16);
    }
  }
  // first K-loop barrier drains these reads before any sP write lands.

  u16* sPw = sQ + wid * 2048;  // per-wave 32 rows x 64 lk (4 KB)

  f32x4 oacc[4][2];
#pragma unroll
  for (int i = 0; i < 4; i++) {
    oacc[i][0] = {0.f, 0.f, 0.f, 0.f};
    oacc[i][1] = {0.f, 0.f, 0.f, 0.f};
  }
  float lsum[2] = {0.f, 0.f};

  for (int lk0 = 0; lk0 < 1024; lk0 += 64) {
#pragma unroll
    for (int p = 0; p < 2; p++) {
      int cl = p * 256 + tid;
      int r = cl >> 3, c = cl & 7, g = c ^ (r & 7);
      gload_lds16(Kb + (size_t)(lk0 + r) * 64 + g * 8, (char*)sK + (p * 256 + wid * 64) * 16);
      gload_lds16(Vb + (size_t)r * 1024 + lk0 + g * 8, (char*)sV + (p * 256 + wid * 64) * 16);
    }
    __syncthreads();

    f32x4 s[4][2];
#pragma unroll
    for (int mt = 0; mt < 4; mt++) {
      s[mt][0] = {0.f, 0.f, 0.f, 0.f};
      s[mt][1] = {0.f, 0.f, 0.f, 0.f};
    }
#pragma unroll
    for (int ks = 0; ks < 2; ks++) {
#pragma unroll
      for (int mt = 0; mt < 4; mt++) {
        int row = mt * 16 + l16;
        int ch = (ks * 4 + quad) ^ (row & 7);
        bf16x8 a = *(const bf16x8*)((const char*)sK + row * 128 + ch * 16);
        s[mt][0] = MFMA16(a, bq[0][ks], s[mt][0]);
        s[mt][1] = MFMA16(a, bq[1][ks], s[mt][1]);
      }
    }

#pragma unroll
    for (int qf = 0; qf < 2; qf++) {
      int row = qf * 16 + l16;
#pragma unroll
      for (int mt = 0; mt < 4; mt++) {
        float p0 = __expf(s[mt][qf][0]);
        float p1 = __expf(s[mt][qf][1]);
        float p2 = __expf(s[mt][qf][2]);
        float p3 = __expf(s[mt][qf][3]);
        lsum[qf] += (p0 + p1) + (p2 + p3);
        ushort4 st;
        st.x = f2bf(p0); st.y = f2bf(p1); st.z = f2bf(p2); st.w = f2bf(p3);
        int ch = (2 * mt + (quad >> 1)) ^ (row & 7);
        *(ushort4*)((char*)sPw + row * 128 + ch * 16 + (quad & 1) * 8) = st;
      }
    }
    asm volatile("s_waitcnt lgkmcnt(0)" ::: "memory");  // same-wave P write->read

    bf16x8 bp[2][2];
#pragma unroll
    for (int qf = 0; qf < 2; qf++) {
      int row = qf * 16 + l16;
#pragma unroll
      for (int c = 0; c < 2; c++) {
        int ch = (c * 4 + quad) ^ (row & 7);
        bp[qf][c] = *(const bf16x8*)((const char*)sPw + row * 128 + ch * 16);
      }
    }
#pragma unroll
    for (int c = 0; c < 2; c++) {
#pragma unroll
      for (int mt = 0; mt < 4; mt++) {
        int row = mt * 16 + l16;
        int ch = (c * 4 + quad) ^ (row & 7);
        bf16x8 a = *(const bf16x8*)((const char*)sV + row * 128 + ch * 16);
        oacc[mt][0] = MFMA16(a, bp[0][c], oacc[mt][0]);
        oacc[mt][1] = MFMA16(a, bp[1][c], oacc[mt][1]);
      }
    }
    __syncthreads();
  }

#pragma unroll
  for (int qf = 0; qf < 2; qf++) {
    lsum[qf] += __shfl_xor(lsum[qf], 16, 64);
    lsum[qf] += __shfl_xor(lsum[qf], 32, 64);
  }
  float inv0 = 1.f / lsum[0], inv1 = 1.f / lsum[1];

  int b = bh >> 4, h = bh & 15;
#pragma unroll
  for (int qf = 0; qf < 2; qf++) {
    int qg = q0 + wid * 32 + qf * 16 + l16;
    float inv = qf ? inv1 : inv0;
#pragma unroll
    for (int mt = 0; mt < 4; mt++) {
      int dk = mt * 16 + quad * 4;
      ushort4 st;
      st.x = f2bf(oacc[mt][qf][0] * inv);
      st.y = f2bf(oacc[mt][qf][1] * inv);
      st.z = f2bf(oacc[mt][qf][2] * inv);
      st.w = f2bf(oacc[mt][qf][3] * inv);
      *(ushort4*)(CTX + (((size_t)(b * 1024 + qg) * 16 + h) * 64 + dk)) = st;
    }
  }
}

// ---------------------------------------------------------------------------
extern "C" void kernel_launch(void* const* d_in, const int* in_sizes, int n_in,
                              void* d_out, int out_size, void* d_ws, size_t ws_size,
                              hipStream_t stream) {
  (void)in_sizes; (void)n_in; (void)out_size; (void)ws_size;
  const float* query = (const float*)d_in[0];
  const float* key_ = (const float*)d_in[1];
  const float* value = (const float*)d_in[2];
  const float* Wq = (const float*)d_in[3];
  const float* Wk = (const float*)d_in[4];
  const float* Wv = (const float*)d_in[5];
  const float* Wo = (const float*)d_in[6];
  const float* bo = (const float*)d_in[7];

  u16* ws = (u16*)d_ws;
  u16* WT = ws;                   // 4 x [1024][1024] bf16 = 8 MB
  u16* X = ws + 4194304;          // 3 x [8192][1024] bf16 (Xq,Xk,Xv)
  u16* Qw = ws + 29360128;        // [B,H,L,DK]
  u16* Kw = ws + 37748736;        // [B,H,L,DK]
  u16* Vw = ws + 46137344;        // [B,H,DK,L]   (total ws need: 109051904 B)
  u16* Cw = X;                    // alias Xq (dead after projections)
  float* outp = (float*)d_out;

  prep<<<25600, 256, 0, stream>>>(Wq, Wk, Wv, Wo, query, key_, value, ws);
  gemm_qkv<<<dim3(8, 64, 3), 256, 0, stream>>>(WT, X, Qw, Kw, Vw);
  attn_k<<<dim3(8, 128), 256, 0, stream>>>(Qw, Kw, Vw, Cw);
  gemm_out<<<dim3(8, 64), 256, 0, stream>>>(WT + 3145728, Cw, outp, bo);
}